// Round 2
// baseline (158.759 us; speedup 1.0000x reference)
//
#include <hip/hip_runtime.h>

// FP8 e4m3 (IEEE variant, top exponent excluded -> max level 240) fake-quantization:
//   ema = max|x| (whole tensor), s = max(ema/240, 1e-8)
//   xq  = nearest_level(x/s) * s   (ties -> lower-valued level)
//
// Level grid: subnormals + bottom binade uniform at step 2^-9; binade [2^e, 2^(e+1))
// uniform at step 2^(e-3); top binade [128, 240] step 16. All steps are powers of
// two, so nearest-level = ceil(v/step - 0.5) * step with every intermediate exact
// in f32 (ties resolve to the lower-valued level, matching argmin-first-occurrence).
//
// Pass 1: global absmax reduction (float4 loads, wave reduce, atomicMax on bits).
// Pass 2: quantize.

__global__ __launch_bounds__(256) void fp8q_absmax_kernel(
    const float4* __restrict__ x4, unsigned int* __restrict__ out_bits,
    const float* __restrict__ x_tail, int n4, int ntail)
{
    int tid = blockIdx.x * blockDim.x + threadIdx.x;
    int stride = gridDim.x * blockDim.x;
    float m = 0.0f;
    for (int i = tid; i < n4; i += stride) {
        float4 v = x4[i];
        m = fmaxf(m, fmaxf(fmaxf(fabsf(v.x), fabsf(v.y)),
                           fmaxf(fabsf(v.z), fabsf(v.w))));
    }
    if (tid < ntail) m = fmaxf(m, fabsf(x_tail[tid]));  // leftover (<4) elements
    // 64-lane wave reduction
    #pragma unroll
    for (int off = 32; off > 0; off >>= 1)
        m = fmaxf(m, __shfl_xor(m, off));
    if ((threadIdx.x & 63) == 0)
        atomicMax(out_bits, __float_as_uint(m));   // all values >= 0: uint order == float order
}

__device__ __forceinline__ float fp8q_quant1(float x, float s)
{
    float v = x / s;                               // IEEE div: bit-matches reference x/s
    v = fminf(fmaxf(v, -240.0f), 240.0f);          // saturate at max level (E=1..14 only)
    float m = fabsf(v);
    int e  = (int)(__float_as_uint(m) >> 23) - 127; // unbiased exponent (m=0 -> -127)
    int se = e - 3;                                 // step = 2^(e-3) within binade
    if (se < -9) se = -9;                           // subnormal region: uniform step 2^-9
    float step     = __uint_as_float((unsigned int)(se + 127) << 23);
    float inv_step = __uint_as_float((unsigned int)(127 - se) << 23);
    float k = v * inv_step;                         // exact (pow2 scale), |k| <= 16
    float n = ceilf(k - 0.5f);                      // round-half-to-lower-value (ref tie rule)
    return (n * step) * s;                          // n*step is exactly the level
}

__global__ __launch_bounds__(256) void fp8q_quant_kernel(
    const float4* __restrict__ x4, float4* __restrict__ o4,
    const float* __restrict__ x_tail, float* __restrict__ o_tail,
    const unsigned int* __restrict__ ema_bits, int n4, int ntail)
{
    float ema = __uint_as_float(*ema_bits);
    float s = fmaxf(ema / 240.0f, 1e-8f);           // 240 + 1e-12 == 240.0f in f32
    int tid = blockIdx.x * blockDim.x + threadIdx.x;
    int stride = gridDim.x * blockDim.x;
    for (int i = tid; i < n4; i += stride) {
        float4 v = x4[i];
        float4 r;
        r.x = fp8q_quant1(v.x, s);
        r.y = fp8q_quant1(v.y, s);
        r.z = fp8q_quant1(v.z, s);
        r.w = fp8q_quant1(v.w, s);
        o4[i] = r;
    }
    if (tid < ntail) o_tail[tid] = fp8q_quant1(x_tail[tid], s);
}

extern "C" void kernel_launch(void* const* d_in, const int* in_sizes, int n_in,
                              void* d_out, int out_size, void* d_ws, size_t ws_size,
                              hipStream_t stream)
{
    const float* x = (const float*)d_in[0];
    float* out = (float*)d_out;
    int n = in_sizes[0];
    int n4 = n >> 2;
    int ntail = n & 3;
    const float* x_tail = x + (size_t)n4 * 4;
    float* o_tail = out + (size_t)n4 * 4;

    unsigned int* ema_bits = (unsigned int*)d_ws;
    hipMemsetAsync(ema_bits, 0, sizeof(unsigned int), stream);

    const int threads = 256;
    int blocks = (n4 + threads - 1) / threads;
    if (blocks > 2048) blocks = 2048;
    if (blocks < 1) blocks = 1;

    fp8q_absmax_kernel<<<blocks, threads, 0, stream>>>(
        (const float4*)x, ema_bits, x_tail, n4, ntail);
    fp8q_quant_kernel<<<blocks, threads, 0, stream>>>(
        (const float4*)x, (float4*)out, x_tail, o_tail, ema_bits, n4, ntail);
}

// Round 3
// 74.382 us; speedup vs baseline: 2.1344x; 2.1344x over previous
//
#include <hip/hip_runtime.h>

// FP8 e4m3 (IEEE variant, top exponent excluded -> max level 240) fake-quantization:
//   ema = max|x| (whole tensor), s = max(ema/240, 1e-8)
//   xq  = nearest_level(x/s) * s   (ties -> lower-valued level)
//
// Level grid: subnormals + bottom binade uniform at step 2^-9; binade [2^e, 2^(e+1))
// uniform at step 2^(e-3); top binade [128, 240] step 16. All steps are powers of
// two, so nearest-level = ceil(v/step - 0.5) * step with every intermediate exact
// in f32 (ties resolve to the lower-valued level, matching argmin-first-occurrence).
//
// Stage 1: per-wave partial absmax -> plain stores to d_ws (NO contended atomics:
//          8192 single-address device atomics cost ~125us serialized — measured R2).
// Stage 2: one block reduces partials, writes final scale s.
// Stage 3: quantize.

#define FP8Q_THREADS 256
#define FP8Q_MAXBLOCKS 2048

__global__ __launch_bounds__(FP8Q_THREADS) void fp8q_absmax_kernel(
    const float4* __restrict__ x4, float* __restrict__ partials,
    const float* __restrict__ x_tail, int n4, int ntail)
{
    int tid = blockIdx.x * blockDim.x + threadIdx.x;
    int stride = gridDim.x * blockDim.x;
    float m = 0.0f;
    for (int i = tid; i < n4; i += stride) {
        float4 v = x4[i];
        m = fmaxf(m, fmaxf(fmaxf(fabsf(v.x), fabsf(v.y)),
                           fmaxf(fabsf(v.z), fabsf(v.w))));
    }
    if (tid < ntail) m = fmaxf(m, fabsf(x_tail[tid]));  // leftover (<4) elements
    // 64-lane wave reduction
    #pragma unroll
    for (int off = 32; off > 0; off >>= 1)
        m = fmaxf(m, __shfl_xor(m, off));
    if ((threadIdx.x & 63) == 0)
        partials[blockIdx.x * (FP8Q_THREADS / 64) + (threadIdx.x >> 6)] = m;
}

__global__ __launch_bounds__(FP8Q_THREADS) void fp8q_reduce_kernel(
    const float* __restrict__ partials, float* __restrict__ scale_out, int np)
{
    __shared__ float smem[FP8Q_THREADS / 64];
    float m = 0.0f;
    for (int i = threadIdx.x; i < np; i += FP8Q_THREADS)
        m = fmaxf(m, partials[i]);
    #pragma unroll
    for (int off = 32; off > 0; off >>= 1)
        m = fmaxf(m, __shfl_xor(m, off));
    if ((threadIdx.x & 63) == 0) smem[threadIdx.x >> 6] = m;
    __syncthreads();
    if (threadIdx.x == 0) {
        float mm = smem[0];
        #pragma unroll
        for (int w = 1; w < FP8Q_THREADS / 64; ++w) mm = fmaxf(mm, smem[w]);
        *scale_out = fmaxf(mm / 240.0f, 1e-8f);   // 240 + 1e-12 == 240.0f in f32
    }
}

__device__ __forceinline__ float fp8q_quant1(float x, float s)
{
    float v = x / s;                               // IEEE div: bit-matches reference x/s
    v = fminf(fmaxf(v, -240.0f), 240.0f);          // saturate at max level (E=1..14 only)
    float m = fabsf(v);
    int e  = (int)(__float_as_uint(m) >> 23) - 127; // unbiased exponent (m=0 -> -127)
    int se = e - 3;                                 // step = 2^(e-3) within binade
    if (se < -9) se = -9;                           // subnormal region: uniform step 2^-9
    float step     = __uint_as_float((unsigned int)(se + 127) << 23);
    float inv_step = __uint_as_float((unsigned int)(127 - se) << 23);
    float k = v * inv_step;                         // exact (pow2 scale), |k| <= 16
    float n = ceilf(k - 0.5f);                      // round-half-to-lower-value (ref tie rule)
    return (n * step) * s;                          // n*step is exactly the level
}

__global__ __launch_bounds__(FP8Q_THREADS) void fp8q_quant_kernel(
    const float4* __restrict__ x4, float4* __restrict__ o4,
    const float* __restrict__ x_tail, float* __restrict__ o_tail,
    const float* __restrict__ scale_p, int n4, int ntail)
{
    float s = *scale_p;
    int tid = blockIdx.x * blockDim.x + threadIdx.x;
    int stride = gridDim.x * blockDim.x;
    for (int i = tid; i < n4; i += stride) {
        float4 v = x4[i];
        float4 r;
        r.x = fp8q_quant1(v.x, s);
        r.y = fp8q_quant1(v.y, s);
        r.z = fp8q_quant1(v.z, s);
        r.w = fp8q_quant1(v.w, s);
        o4[i] = r;
    }
    if (tid < ntail) o_tail[tid] = fp8q_quant1(x_tail[tid], s);
}

extern "C" void kernel_launch(void* const* d_in, const int* in_sizes, int n_in,
                              void* d_out, int out_size, void* d_ws, size_t ws_size,
                              hipStream_t stream)
{
    const float* x = (const float*)d_in[0];
    float* out = (float*)d_out;
    int n = in_sizes[0];
    int n4 = n >> 2;
    int ntail = n & 3;
    const float* x_tail = x + (size_t)n4 * 4;
    float* o_tail = out + (size_t)n4 * 4;

    // workspace layout: [0] = final scale, [64..] = per-wave partials
    float* scale_p = (float*)d_ws;
    float* partials = (float*)d_ws + 64;

    int blocks = (n4 + FP8Q_THREADS - 1) / FP8Q_THREADS;
    if (blocks > FP8Q_MAXBLOCKS) blocks = FP8Q_MAXBLOCKS;
    if (blocks < 1) blocks = 1;
    int np = blocks * (FP8Q_THREADS / 64);

    fp8q_absmax_kernel<<<blocks, FP8Q_THREADS, 0, stream>>>(
        (const float4*)x, partials, x_tail, n4, ntail);
    fp8q_reduce_kernel<<<1, FP8Q_THREADS, 0, stream>>>(partials, scale_p, np);
    fp8q_quant_kernel<<<blocks, FP8Q_THREADS, 0, stream>>>(
        (const float4*)x, (float4*)out, x_tail, o_tail, scale_p, n4, ntail);
}

// Round 4
// 68.924 us; speedup vs baseline: 2.3034x; 1.0792x over previous
//
#include <hip/hip_runtime.h>

// FP8 e4m3 (IEEE variant, top exponent excluded -> max level 240) fake-quantization:
//   ema = max|x| (whole tensor), s = max(ema/240, 1e-8)
//   xq  = nearest_level(x/s) * s   (ties -> lower-valued level)
//
// Level grid: uniform step 2^(e-3) per binade (clamped to 2^-9 in the subnormal
// region, which joins the bottom binade seamlessly); top binade [128, 240] step 16.
// All steps are powers of two, so nearest-level = ceil(v/step - 0.5) * step with
// every intermediate exact in f32 (ties -> lower level = argmin first occurrence).
//
// Structure (2 kernels, no atomics):
//   A: per-block absmax -> partials[block] (plain stores; R2 showed 8192
//      single-address atomics cost ~125us serialized).
//   B: every block redundantly reduces the 2048 partials (8 KB, L2-hot, ~1-2us
//      overlapped) -> s, then quantizes with NON-TEMPORAL stores so the 134 MB
//      output doesn't evict x from the 256 MB L3 before pass-2 re-reads it.

typedef float f32x4 __attribute__((ext_vector_type(4)));

#define FP8Q_THREADS 256
#define FP8Q_MAXBLOCKS 2048

__global__ __launch_bounds__(FP8Q_THREADS) void fp8q_absmax_kernel(
    const f32x4* __restrict__ x4, float* __restrict__ partials,
    const float* __restrict__ x_tail, int n4, int ntail)
{
    __shared__ float smem[FP8Q_THREADS / 64];
    int tid = blockIdx.x * blockDim.x + threadIdx.x;
    int stride = gridDim.x * blockDim.x;
    float m = 0.0f;
    for (int i = tid; i < n4; i += stride) {
        f32x4 v = x4[i];
        m = fmaxf(m, fmaxf(fmaxf(fabsf(v.x), fabsf(v.y)),
                           fmaxf(fabsf(v.z), fabsf(v.w))));
    }
    if (tid < ntail) m = fmaxf(m, fabsf(x_tail[tid]));  // leftover (<4) elements
    #pragma unroll
    for (int off = 32; off > 0; off >>= 1)
        m = fmaxf(m, __shfl_xor(m, off));
    if ((threadIdx.x & 63) == 0) smem[threadIdx.x >> 6] = m;
    __syncthreads();
    if (threadIdx.x == 0) {
        float mm = smem[0];
        #pragma unroll
        for (int w = 1; w < FP8Q_THREADS / 64; ++w) mm = fmaxf(mm, smem[w]);
        partials[blockIdx.x] = mm;   // one plain store per block
    }
}

__device__ __forceinline__ float fp8q_quant1(float x, float s)
{
    float v = x / s;                               // IEEE div: bit-matches reference x/s
    v = fminf(fmaxf(v, -240.0f), 240.0f);          // saturate at max level (E=1..14 only)
    float m = fabsf(v);
    int e  = (int)(__float_as_uint(m) >> 23) - 127; // unbiased exponent (m=0 -> -127)
    int se = e - 3;                                 // step = 2^(e-3) within binade
    if (se < -9) se = -9;                           // subnormal region: uniform step 2^-9
    float step     = __uint_as_float((unsigned int)(se + 127) << 23);
    float inv_step = __uint_as_float((unsigned int)(127 - se) << 23);
    float k = v * inv_step;                         // exact (pow2 scale), |k| <= 16
    float n = ceilf(k - 0.5f);                      // round-half-to-lower-value (ref tie rule)
    return (n * step) * s;                          // n*step is exactly the level
}

__global__ __launch_bounds__(FP8Q_THREADS) void fp8q_quant_kernel(
    const f32x4* __restrict__ x4, f32x4* __restrict__ o4,
    const float* __restrict__ x_tail, float* __restrict__ o_tail,
    const float* __restrict__ partials, int np, int n4, int ntail)
{
    __shared__ float smem[FP8Q_THREADS / 64];
    __shared__ float s_shared;
    // redundant per-block reduce of block partials (visible via stream ordering)
    float m = 0.0f;
    for (int i = threadIdx.x; i < np; i += FP8Q_THREADS)
        m = fmaxf(m, partials[i]);
    #pragma unroll
    for (int off = 32; off > 0; off >>= 1)
        m = fmaxf(m, __shfl_xor(m, off));
    if ((threadIdx.x & 63) == 0) smem[threadIdx.x >> 6] = m;
    __syncthreads();
    if (threadIdx.x == 0) {
        float mm = smem[0];
        #pragma unroll
        for (int w = 1; w < FP8Q_THREADS / 64; ++w) mm = fmaxf(mm, smem[w]);
        s_shared = fmaxf(mm / 240.0f, 1e-8f);      // 240 + 1e-12 == 240.0f in f32
    }
    __syncthreads();
    float s = s_shared;

    int tid = blockIdx.x * blockDim.x + threadIdx.x;
    int stride = gridDim.x * blockDim.x;
    for (int i = tid; i < n4; i += stride) {
        f32x4 v = x4[i];
        f32x4 r;
        r.x = fp8q_quant1(v.x, s);
        r.y = fp8q_quant1(v.y, s);
        r.z = fp8q_quant1(v.z, s);
        r.w = fp8q_quant1(v.w, s);
        __builtin_nontemporal_store(r, &o4[i]);    // don't evict x from L3
    }
    if (tid < ntail) o_tail[tid] = fp8q_quant1(x_tail[tid], s);
}

extern "C" void kernel_launch(void* const* d_in, const int* in_sizes, int n_in,
                              void* d_out, int out_size, void* d_ws, size_t ws_size,
                              hipStream_t stream)
{
    const float* x = (const float*)d_in[0];
    float* out = (float*)d_out;
    int n = in_sizes[0];
    int n4 = n >> 2;
    int ntail = n & 3;
    const float* x_tail = x + (size_t)n4 * 4;
    float* o_tail = out + (size_t)n4 * 4;

    float* partials = (float*)d_ws;   // one float per block

    int blocks = (n4 + FP8Q_THREADS - 1) / FP8Q_THREADS;
    if (blocks > FP8Q_MAXBLOCKS) blocks = FP8Q_MAXBLOCKS;
    if (blocks < 1) blocks = 1;

    fp8q_absmax_kernel<<<blocks, FP8Q_THREADS, 0, stream>>>(
        (const f32x4*)x, partials, x_tail, n4, ntail);
    fp8q_quant_kernel<<<blocks, FP8Q_THREADS, 0, stream>>>(
        (const f32x4*)x, (f32x4*)out, x_tail, o_tail, partials, blocks, n4, ntail);
}